// Round 4
// baseline (516.631 us; speedup 1.0000x reference)
//
#include <hip/hip_runtime.h>

// ---------------------------------------------------------------------------
// HOI top-k, R=262144 x K=117, topk=100, thresh=0.05
//
//  K1 k_main   : block-chunked streaming pass. Block b owns RPB=128 rows;
//                stages bs[r]=ps*os into LDS once, then streams the chunk's
//                hoi float4s (coalesced, 4 loads in flight). Hot loop touches
//                ONLY the hoi stream + LDS. Window histogram (80 bins,
//                s>0.75) flushed to 32 replicated global histograms.
//                Candidates >= 0.898 (bin G_REL) -> global buffer. The LAST
//                block (atomic done-counter) reduces replicas, finds exact
//                cutoff bin T, filters+bitonic-sorts candidates in LDS
//                (value desc, index asc = stable top_k order), writes output.
//  K2 k_safety : 1 block; early-exits unless k_main flagged slow path.
//                Exact full recompute (576-bin hist) — correctness net.
// ---------------------------------------------------------------------------

#define NB        576          // full histogram bins (top-16 float bits - base)
#define BIN_BASE  15692        // (bits of 0.05f) >> 16
#define WLO       500          // window start: bin of 0.75f
#define WN        80           // window bins (576-500=76, padded)
#define VLO       0.75f        // value at bin WLO
#define G_REL     538          // bin of 0.8984375 -> opportunistic collect
#define FCAP      2048         // sort capacity (power of 2), 16 KiB LDS
#define NREP      32           // histogram replicas
#define REPS      96           // replica stride (ints) -> distinct lines
#define RPB       128          // rows per block (128*117 = 3744 float4 exact)
#define THRESH    0.05f
#define NEG_INF   __int_as_float(0xFF800000)

__device__ __forceinline__ int bin_of(float s) {
  // valid only for s > 0 (positive floats: bit order == value order)
  int b = (int)(__float_as_uint(s) >> 16) - BIN_BASE;
  return b > (NB - 1) ? (NB - 1) : b;
}

// ctrl layout (ints): [0]=cand_cnt  [1]=done_counter  [2]=T  [3]=slow_flag

template <int KC>
__global__ __launch_bounds__(256) void k_main(
    const float* __restrict__ hoi, const float* __restrict__ ps,
    const float* __restrict__ os, const float4* __restrict__ pbox,
    const float4* __restrict__ obox, const int* __restrict__ ocls,
    int R, int Kc, int* __restrict__ ctrl, int* __restrict__ rep,
    float* __restrict__ cand_v, int* __restrict__ cand_i, int cap,
    float* __restrict__ out, int topk) {
  __shared__ float lbs[RPB];
  __shared__ int lh[WN];
  __shared__ int wh[WN];
  __shared__ float sv[FCAP];
  __shared__ int si[FCAP];
  __shared__ int s_misc[4];    // [0]=amLast [1]=T [2]=cand n [3]=scnt

  const int k = KC ? KC : Kc;
  const int r0 = blockIdx.x * RPB;
  const int nr = (R - r0) < RPB ? (R - r0) : RPB;

  // stage bs for this block's rows (coalesced, once)
  for (int r = threadIdx.x; r < nr; r += blockDim.x)
    lbs[r] = ps[r0 + r] * os[r0 + r];   // box_scores = p*o (matches ref)
  if (threadIdx.x < WN) lh[threadIdx.x] = 0;
  __syncthreads();

  const int base = r0 * k;             // chunk start (float index), 16B-aligned
  const int nfloat = nr * k;
  const int nf4 = nfloat >> 2;
  const float4* c4 = (const float4*)(hoi + base);

  auto process = [&](int t, const float4& h) {
    int i0 = 4 * t;
    int q = i0 / k;                    // constant k -> magic mul
    int rem = i0 - q * k;
    float bsa = lbs[q];                // index-derived LDS reads: issue early
    float bsb = lbs[(rem + 3 >= k) ? q + 1 : q];
    float vals[4] = {h.x, h.y, h.z, h.w};
#pragma unroll
    for (int j = 0; j < 4; ++j) {
      float s = vals[j] * ((rem + j >= k) ? bsb : bsa);  // = hoi*bs (exact ref)
      if (s > VLO) {
        int b = bin_of(s);
        atomicAdd(&lh[b - WLO], 1);
        if (b >= G_REL) {
          int slot = atomicAdd(&ctrl[0], 1);
          if (slot < cap) { cand_v[slot] = s; cand_i[slot] = base + i0 + j; }
        }
      }
    }
  };

  const int BD = blockDim.x;
  for (int t0 = threadIdx.x; t0 < nf4; t0 += 4 * BD) {
    int t1 = t0 + BD, t2 = t0 + 2 * BD, t3 = t0 + 3 * BD;
    float4 h0 = c4[t0];                // 4 independent loads in flight
    float4 h1 = c4[t1 < nf4 ? t1 : t0];
    float4 h2 = c4[t2 < nf4 ? t2 : t0];
    float4 h3 = c4[t3 < nf4 ? t3 : t0];
    process(t0, h0);
    if (t1 < nf4) process(t1, h1);
    if (t2 < nf4) process(t2, h2);
    if (t3 < nf4) process(t3, h3);
  }
  // scalar tail (nfloat % 4; empty when nr==RPB=128 since 128*117%4==0)
  for (int i = (nf4 << 2) + threadIdx.x; i < nfloat; i += BD) {
    int q = i / k;
    float s = hoi[base + i] * lbs[q];
    if (s > VLO) {
      int b = bin_of(s);
      atomicAdd(&lh[b - WLO], 1);
      if (b >= G_REL) {
        int slot = atomicAdd(&ctrl[0], 1);
        if (slot < cap) { cand_v[slot] = s; cand_i[slot] = base + i; }
      }
    }
  }

  __syncthreads();
  if (threadIdx.x < WN) {              // 32-way replicated flush
    int c = lh[threadIdx.x];
    if (c) atomicAdd(&rep[(blockIdx.x & (NREP - 1)) * REPS + threadIdx.x], c);
  }
  __threadfence();                     // release: hist + cand visible
  __syncthreads();
  if (threadIdx.x == 0) {
    int prev = atomicAdd(&ctrl[1], 1);
    s_misc[0] = (prev == (int)gridDim.x - 1) ? 1 : 0;
  }
  __syncthreads();
  if (!s_misc[0]) return;

  // ---------------- finishing block (last to complete) ----------------
  __threadfence();                     // acquire
  if (threadIdx.x < WN) {
    int sum = 0;
#pragma unroll
    for (int r = 0; r < NREP; ++r) sum += rep[r * REPS + threadIdx.x];
    wh[threadIdx.x] = sum;
  }
  __syncthreads();
  if (threadIdx.x == 0) {
    int cum = 0, T = -1;
    for (int b = WN - 1; b >= 0; --b) {
      cum += wh[b];
      if (T < 0 && cum >= topk) T = b + WLO;
    }
    int cnt = ctrl[0];
    int fast = (T >= G_REL && cnt <= cap) ? 1 : 0;
    ctrl[2] = T;
    ctrl[3] = fast ? 0 : 1;
    s_misc[1] = fast ? T : -1;
    s_misc[2] = cnt > cap ? cap : cnt;
    s_misc[3] = 0;
  }
  __syncthreads();
  const int T = s_misc[1];
  if (T < 0) return;                   // slow path -> k_safety
  const int n = s_misc[2];
  for (int t = threadIdx.x; t < n; t += blockDim.x) {
    float v = cand_v[t];
    if (bin_of(v) >= T) {
      int slot = atomicAdd(&s_misc[3], 1);
      if (slot < FCAP) { sv[slot] = v; si[slot] = cand_i[t]; }
    }
  }
  __syncthreads();
  int m = s_misc[3];
  if (m > FCAP) {                      // degenerate -> safety net
    if (threadIdx.x == 0) ctrl[3] = 1;
    return;
  }
  int P = 128;
  while (P < m) P <<= 1;
  for (int t = m + threadIdx.x; t < P; t += blockDim.x) {
    sv[t] = NEG_INF;
    si[t] = 0x7FFFFFFF;
  }
  for (int kk = 2; kk <= P; kk <<= 1) {
    for (int j = kk >> 1; j > 0; j >>= 1) {
      __syncthreads();
      for (int i = threadIdx.x; i < P; i += blockDim.x) {
        int l = i ^ j;
        if (l > i) {
          float vi = sv[i], vl = sv[l];
          int ii = si[i], il = si[l];
          bool before = (vi > vl) || (vi == vl && ii < il);
          if (((i & kk) == 0) != before) {
            sv[i] = vl; sv[l] = vi; si[i] = il; si[l] = ii;
          }
        }
      }
    }
  }
  __syncthreads();
  if ((int)threadIdx.x < topk) {
    int o = threadIdx.x;
    float v = sv[o];
    int idx = si[o];
    bool valid = (idx != 0x7FFFFFFF) && (v > THRESH);
    int safe = valid ? idx : 0;
    int pair = safe / Kc;
    int act = safe - pair * Kc;
    float4 pb = pbox[pair];
    float4 ob = obox[pair];
    out[o] = valid ? v : 0.0f;
    float* pdst = out + topk + 4 * o;
    pdst[0] = pb.x; pdst[1] = pb.y; pdst[2] = pb.z; pdst[3] = pb.w;
    float* odst = out + 5 * topk + 4 * o;
    odst[0] = ob.x; odst[1] = ob.y; odst[2] = ob.z; odst[3] = ob.w;
    out[9 * topk + o] = (float)ocls[pair];
    out[10 * topk + o] = (float)act;
    out[11 * topk + o] = valid ? 1.0f : 0.0f;
  }
}

// Exact fallback; normally exits immediately (ctrl[3]==0).
__global__ __launch_bounds__(1024) void k_safety(
    const float* __restrict__ hoi, const float* __restrict__ ps,
    const float* __restrict__ os, const float4* __restrict__ pbox,
    const float4* __restrict__ obox, const int* __restrict__ ocls,
    int N, int Kc, const int* __restrict__ ctrl, float* __restrict__ out,
    int topk) {
  if (ctrl[3] == 0) return;
  __shared__ int lh[NB];
  __shared__ float sv[FCAP];
  __shared__ int si[FCAP];
  __shared__ int sT, scnt;
  for (int b = threadIdx.x; b < NB; b += blockDim.x) lh[b] = 0;
  if (threadIdx.x == 0) scnt = 0;
  __syncthreads();
  for (int i = threadIdx.x; i < N; i += blockDim.x) {
    int q = i / Kc;
    float s = hoi[i] * (ps[q] * os[q]);
    if (s > THRESH) atomicAdd(&lh[bin_of(s)], 1);
  }
  __syncthreads();
  if (threadIdx.x == 0) {
    int cum = 0, T = 0;
    for (int b = NB - 1; b >= 0; --b) {
      cum += lh[b];
      if (cum >= topk) { T = b; break; }
    }
    sT = T;
  }
  __syncthreads();
  const int T = sT;
  for (int i = threadIdx.x; i < N; i += blockDim.x) {
    int q = i / Kc;
    float s = hoi[i] * (ps[q] * os[q]);
    if (s > THRESH && bin_of(s) >= T) {
      int slot = atomicAdd(&scnt, 1);
      if (slot < FCAP) { sv[slot] = s; si[slot] = i; }
    }
  }
  __syncthreads();
  int m = scnt > FCAP ? FCAP : scnt;
  int P = 128;
  while (P < m) P <<= 1;
  for (int t = m + threadIdx.x; t < P; t += blockDim.x) {
    sv[t] = NEG_INF;
    si[t] = 0x7FFFFFFF;
  }
  for (int kk = 2; kk <= P; kk <<= 1) {
    for (int j = kk >> 1; j > 0; j >>= 1) {
      __syncthreads();
      for (int i = threadIdx.x; i < P; i += blockDim.x) {
        int l = i ^ j;
        if (l > i) {
          float vi = sv[i], vl = sv[l];
          int ii = si[i], il = si[l];
          bool before = (vi > vl) || (vi == vl && ii < il);
          if (((i & kk) == 0) != before) {
            sv[i] = vl; sv[l] = vi; si[i] = il; si[l] = ii;
          }
        }
      }
    }
  }
  __syncthreads();
  if ((int)threadIdx.x < topk) {
    int o = threadIdx.x;
    float v = sv[o];
    int idx = si[o];
    bool valid = (idx != 0x7FFFFFFF) && (v > THRESH);
    int safe = valid ? idx : 0;
    int pair = safe / Kc;
    int act = safe - pair * Kc;
    float4 pb = pbox[pair];
    float4 ob = obox[pair];
    out[o] = valid ? v : 0.0f;
    float* pdst = out + topk + 4 * o;
    pdst[0] = pb.x; pdst[1] = pb.y; pdst[2] = pb.z; pdst[3] = pb.w;
    float* odst = out + 5 * topk + 4 * o;
    odst[0] = ob.x; odst[1] = ob.y; odst[2] = ob.z; odst[3] = ob.w;
    out[9 * topk + o] = (float)ocls[pair];
    out[10 * topk + o] = (float)act;
    out[11 * topk + o] = valid ? 1.0f : 0.0f;
  }
}

extern "C" void kernel_launch(void* const* d_in, const int* in_sizes, int n_in,
                              void* d_out, int out_size, void* d_ws, size_t ws_size,
                              hipStream_t stream) {
  const float* pbox = (const float*)d_in[0];
  const float* obox = (const float*)d_in[1];
  const float* ps   = (const float*)d_in[2];
  const float* os   = (const float*)d_in[3];
  const int*   ocls = (const int*)d_in[4];
  const float* hoi  = (const float*)d_in[5];
  float* out = (float*)d_out;

  const int R    = in_sizes[2];
  const int N    = in_sizes[5];
  const int Kc   = N / R;              // 117
  const int topk = out_size / 12;      // 100

  // ws: ctrl[64 ints] @0 | replicas 32x96 ints @256 | cand_v/cand_i @12544
  int* ctrl = (int*)d_ws;
  int* rep  = (int*)((char*)d_ws + 256);
  float* cand_v = (float*)((char*)d_ws + 12544);
  size_t cand_budget = (ws_size > 12544) ? (ws_size - 12544) / 8 : 1024;
  int cap = cand_budget > 8192 ? 8192 : (int)cand_budget;
  int* cand_i = (int*)((char*)d_ws + 12544 + (size_t)cap * sizeof(float));

  hipMemsetAsync(d_ws, 0, 12544, stream);   // zero ctrl + replicas

  const int nblocks = (R + RPB - 1) / RPB;  // 2048 for R=262144
  if (Kc == 117) {
    k_main<117><<<nblocks, 256, 0, stream>>>(
        hoi, ps, os, (const float4*)pbox, (const float4*)obox, ocls, R, Kc,
        ctrl, rep, cand_v, cand_i, cap, out, topk);
  } else {
    k_main<0><<<nblocks, 256, 0, stream>>>(
        hoi, ps, os, (const float4*)pbox, (const float4*)obox, ocls, R, Kc,
        ctrl, rep, cand_v, cand_i, cap, out, topk);
  }
  k_safety<<<1, 1024, 0, stream>>>(hoi, ps, os, (const float4*)pbox,
                                   (const float4*)obox, ocls, N, Kc, ctrl,
                                   out, topk);
}

// Round 5
// 222.030 us; speedup vs baseline: 2.3269x; 2.3269x over previous
//
#include <hip/hip_runtime.h>

// ---------------------------------------------------------------------------
// HOI top-k, R=262144 x K=117, topk=100, thresh=0.05
//
//  K1 k_main : flat grid-stride streaming pass, 8 independent float4 loads in
//              flight. LDS window histogram (80 bins, s>0.75) flushed to 32
//              replicated global histograms (kills same-line atomic drain).
//              Candidates >= 0.898 (bin G_REL) appended to a global buffer.
//              NO fences, NO last-block fusion: kernel-boundary coherence.
//  K2 k_post : 1 block. Reduce replicas -> exact cutoff bin T. Fast path:
//              filter candidates (bin >= T), bitonic sort (value desc, index
//              asc = stable top_k tie order), write all outputs. Slow path
//              (T below collect window / buffer overflow — never on this
//              data): exact single-block recompute with full 576-bin hist.
// ---------------------------------------------------------------------------

#define NB        576          // full histogram bins (top-16 float bits - base)
#define BIN_BASE  15692        // (bits of 0.05f) >> 16
#define WLO       500          // window start: bin of 0.75f
#define WN        80           // window bins (576-500=76, padded)
#define VLO       0.75f        // value at bin WLO
#define G_REL     538          // bin of 0.8984375 -> opportunistic collect
#define FCAP      2048         // sort capacity (power of 2), 16 KiB LDS
#define NREP      32           // histogram replicas
#define REPS      96           // replica stride (ints) -> distinct lines
#define UNROLL    8            // independent float4 loads in flight
#define THRESH    0.05f
#define NEG_INF   __int_as_float(0xFF800000)

__device__ __forceinline__ int bin_of(float s) {
  // valid only for s > 0 (positive floats: bit order == value order)
  int b = (int)(__float_as_uint(s) >> 16) - BIN_BASE;
  return b > (NB - 1) ? (NB - 1) : b;
}

// ctrl layout (ints): [0]=cand_cnt

template <int KC>
__global__ __launch_bounds__(256) void k_main(
    const float4* __restrict__ hoi4, const float* __restrict__ ps,
    const float* __restrict__ os, int N4, int N, int Kc,
    int* __restrict__ ctrl, int* __restrict__ rep,
    float* __restrict__ cand_v, int* __restrict__ cand_i, int cap) {
  __shared__ int lh[WN];
  if (threadIdx.x < WN) lh[threadIdx.x] = 0;
  __syncthreads();

  const int k = KC ? KC : Kc;
  const int TT = gridDim.x * blockDim.x;
  const int tid = blockIdx.x * blockDim.x + threadIdx.x;

  auto process = [&](int t, const float4& h) {
    int i0 = 4 * t;
    int q = i0 / k;                      // constant k -> magic mul
    int rem = i0 - q * k;
    // index-derived addresses: compiler hoists these next to the stream loads
    float bsa = ps[q] * os[q];           // box_scores = p*o (matches ref)
    int qb = (rem + 3 >= k) ? q + 1 : q; // row crossing within the float4
    float bsb = ps[qb] * os[qb];
    float vals[4] = {h.x, h.y, h.z, h.w};
#pragma unroll
    for (int j = 0; j < 4; ++j) {
      float s = vals[j] * ((rem + j >= k) ? bsb : bsa); // = hoi*bs (exact ref)
      if (s > VLO) {
        int b = bin_of(s);
        atomicAdd(&lh[b - WLO], 1);
        if (b >= G_REL) {
          int slot = atomicAdd(&ctrl[0], 1);
          if (slot < cap) { cand_v[slot] = s; cand_i[slot] = i0 + j; }
        }
      }
    }
  };

  for (int t0 = tid; t0 < N4; t0 += UNROLL * TT) {
    float4 h[UNROLL];
#pragma unroll
    for (int j = 0; j < UNROLL; ++j) {   // UNROLL independent loads in flight
      int t = t0 + j * TT;
      h[j] = hoi4[t < N4 ? t : t0];
    }
#pragma unroll
    for (int j = 0; j < UNROLL; ++j) {
      int t = t0 + j * TT;
      if (t < N4) process(t, h[j]);
    }
  }
  // scalar tail (N % 4) — block 0 only (empty when N % 4 == 0)
  if (blockIdx.x == 0) {
    const float* hoi = (const float*)hoi4;
    for (int i = N4 * 4 + threadIdx.x; i < N; i += blockDim.x) {
      int q = i / k;
      float s = hoi[i] * (ps[q] * os[q]);
      if (s > VLO) {
        int b = bin_of(s);
        atomicAdd(&lh[b - WLO], 1);
        if (b >= G_REL) {
          int slot = atomicAdd(&ctrl[0], 1);
          if (slot < cap) { cand_v[slot] = s; cand_i[slot] = i; }
        }
      }
    }
  }
  __syncthreads();
  if (threadIdx.x < WN) {                // 32-way replicated flush
    int c = lh[threadIdx.x];
    if (c) atomicAdd(&rep[(blockIdx.x & (NREP - 1)) * REPS + threadIdx.x], c);
  }
}

__global__ __launch_bounds__(1024) void k_post(
    const float* __restrict__ hoi, const float* __restrict__ ps,
    const float* __restrict__ os, const float4* __restrict__ pbox,
    const float4* __restrict__ obox, const int* __restrict__ ocls,
    int N, int Kc, const int* __restrict__ ctrl, const int* __restrict__ rep,
    const float* __restrict__ cand_v, const int* __restrict__ cand_i,
    int cap, float* __restrict__ out, int topk) {
  __shared__ int wh[NB];       // [0,WN) fast path; full NB on slow path
  __shared__ float sv[FCAP];
  __shared__ int si[FCAP];
  __shared__ int s_T, s_n, s_cnt, s_mode;

  if (threadIdx.x < WN) {      // reduce the 32 replicas
    int sum = 0;
#pragma unroll
    for (int r = 0; r < NREP; ++r) sum += rep[r * REPS + threadIdx.x];
    wh[threadIdx.x] = sum;
  }
  __syncthreads();
  if (threadIdx.x == 0) {
    int cum = 0, T = -1;
    for (int b = WN - 1; b >= 0; --b) {
      cum += wh[b];
      if (T < 0 && cum >= topk) T = b + WLO;
    }
    int cnt = ctrl[0];
    s_mode = (T >= G_REL && cnt <= cap) ? 1 : 0;   // 1 = fast
    s_T = T;
    s_n = cnt > cap ? cap : cnt;
    s_cnt = 0;
  }
  __syncthreads();

  if (s_mode) {
    const int T = s_T, n = s_n;
    for (int t = threadIdx.x; t < n; t += blockDim.x) {
      float v = cand_v[t];
      if (bin_of(v) >= T) {
        int slot = atomicAdd(&s_cnt, 1);
        if (slot < FCAP) { sv[slot] = v; si[slot] = cand_i[t]; }
      }
    }
  } else {
    // slow-but-exact: full histogram + re-collect (correctness net)
    for (int b = threadIdx.x; b < NB; b += blockDim.x) wh[b] = 0;
    __syncthreads();
    for (int i = threadIdx.x; i < N; i += blockDim.x) {
      int q = i / Kc;
      float s = hoi[i] * (ps[q] * os[q]);
      if (s > THRESH) atomicAdd(&wh[bin_of(s)], 1);
    }
    __syncthreads();
    if (threadIdx.x == 0) {
      int cum = 0, T = 0;
      for (int b = NB - 1; b >= 0; --b) {
        cum += wh[b];
        if (cum >= topk) { T = b; break; }
      }
      s_T = T;
    }
    __syncthreads();
    const int T = s_T;
    for (int i = threadIdx.x; i < N; i += blockDim.x) {
      int q = i / Kc;
      float s = hoi[i] * (ps[q] * os[q]);
      if (s > THRESH && bin_of(s) >= T) {
        int slot = atomicAdd(&s_cnt, 1);
        if (slot < FCAP) { sv[slot] = s; si[slot] = i; }
      }
    }
  }
  __syncthreads();

  int m = s_cnt > FCAP ? FCAP : s_cnt;
  int P = 128;                 // >= topk; dynamic power-of-2 sort size
  while (P < m) P <<= 1;
  for (int t = m + threadIdx.x; t < P; t += blockDim.x) {
    sv[t] = NEG_INF;
    si[t] = 0x7FFFFFFF;
  }
  // bitonic sort [0,P): value desc, index asc (stable-top_k tie order)
  for (int kk = 2; kk <= P; kk <<= 1) {
    for (int j = kk >> 1; j > 0; j >>= 1) {
      __syncthreads();
      for (int i = threadIdx.x; i < P; i += blockDim.x) {
        int l = i ^ j;
        if (l > i) {
          float vi = sv[i], vl = sv[l];
          int ii = si[i], il = si[l];
          bool before = (vi > vl) || (vi == vl && ii < il);
          if (((i & kk) == 0) != before) {
            sv[i] = vl; sv[l] = vi; si[i] = il; si[l] = ii;
          }
        }
      }
    }
  }
  __syncthreads();

  if ((int)threadIdx.x < topk) {
    int o = threadIdx.x;
    float v = sv[o];
    int idx = si[o];
    bool valid = (idx != 0x7FFFFFFF) && (v > THRESH);
    int safe = valid ? idx : 0;
    int pair = safe / Kc;
    int act = safe - pair * Kc;
    float4 pb = pbox[pair];
    float4 ob = obox[pair];
    // output: scores[100] | pboxes[400] | oboxes[400] | ocls[100] |
    //         action[100] | valid[100]   (all fp32)
    out[o] = valid ? v : 0.0f;
    float* pdst = out + topk + 4 * o;
    pdst[0] = pb.x; pdst[1] = pb.y; pdst[2] = pb.z; pdst[3] = pb.w;
    float* odst = out + 5 * topk + 4 * o;
    odst[0] = ob.x; odst[1] = ob.y; odst[2] = ob.z; odst[3] = ob.w;
    out[9 * topk + o] = (float)ocls[pair];
    out[10 * topk + o] = (float)act;
    out[11 * topk + o] = valid ? 1.0f : 0.0f;
  }
}

extern "C" void kernel_launch(void* const* d_in, const int* in_sizes, int n_in,
                              void* d_out, int out_size, void* d_ws, size_t ws_size,
                              hipStream_t stream) {
  const float* pbox = (const float*)d_in[0];
  const float* obox = (const float*)d_in[1];
  const float* ps   = (const float*)d_in[2];
  const float* os   = (const float*)d_in[3];
  const int*   ocls = (const int*)d_in[4];
  const float* hoi  = (const float*)d_in[5];
  float* out = (float*)d_out;

  const int R    = in_sizes[2];
  const int N    = in_sizes[5];
  const int Kc   = N / R;              // 117
  const int topk = out_size / 12;      // 100

  // ws: ctrl[64 ints] @0 | replicas 32x96 ints @256 | cand_v/cand_i @12544
  int* ctrl = (int*)d_ws;
  int* rep  = (int*)((char*)d_ws + 256);
  float* cand_v = (float*)((char*)d_ws + 12544);
  size_t cand_budget = (ws_size > 12544) ? (ws_size - 12544) / 8 : 1024;
  int cap = cand_budget > 8192 ? 8192 : (int)cand_budget;
  int* cand_i = (int*)((char*)d_ws + 12544 + (size_t)cap * sizeof(float));

  hipMemsetAsync(d_ws, 0, 12544, stream);   // zero ctrl + replicas

  const int N4 = N / 4;
  if (Kc == 117) {
    k_main<117><<<2048, 256, 0, stream>>>((const float4*)hoi, ps, os, N4, N,
                                          Kc, ctrl, rep, cand_v, cand_i, cap);
  } else {
    k_main<0><<<2048, 256, 0, stream>>>((const float4*)hoi, ps, os, N4, N, Kc,
                                        ctrl, rep, cand_v, cand_i, cap);
  }
  k_post<<<1, 1024, 0, stream>>>(hoi, ps, os, (const float4*)pbox,
                                 (const float4*)obox, ocls, N, Kc, ctrl, rep,
                                 cand_v, cand_i, cap, out, topk);
}

// Round 6
// 215.258 us; speedup vs baseline: 2.4001x; 1.0315x over previous
//
#include <hip/hip_runtime.h>

// ---------------------------------------------------------------------------
// HOI top-k, R=262144 x K=117, topk=100, thresh=0.05
//
//  K1 k_main : block-chunked streaming pass. Block b owns RPB=128 rows
//              (= exactly 3744 float4s). bs[r]=ps*os staged ONCE into LDS as
//              duplicated float2 pairs -> hot loop is 1 global float4 load +
//              1 ds_read_b64 per group (VMEM-issue was the R5 wall: 5 VMEM
//              instrs/group = 150K instrs/CU = 62 us). Window histogram
//              (80 bins, s>0.75) flushed to 32 replicated global histograms.
//              Candidates >= 0.898 (bin G_REL) -> global buffer. NO fences.
//  K2 k_post : 1 block. Reduce replicas -> exact cutoff bin T. Fast path:
//              filter candidates (bin >= T), bitonic sort (value desc, index
//              asc = stable top_k tie order), write outputs. Slow path
//              (T below window / overflow — never on this data): exact
//              single-block recompute with full 576-bin histogram.
// ---------------------------------------------------------------------------

#define NB        576          // full histogram bins (top-16 float bits - base)
#define BIN_BASE  15692        // (bits of 0.05f) >> 16
#define WLO       500          // window start: bin of 0.75f
#define WN        80           // window bins (576-500=76, padded)
#define VLO       0.75f        // value at bin WLO
#define G_REL     538          // bin of 0.8984375 -> opportunistic collect
#define FCAP      2048         // sort capacity (power of 2), 16 KiB LDS
#define NREP      32           // histogram replicas
#define REPS      96           // replica stride (ints) -> distinct lines
#define RPB       128          // rows per block (128*117 floats = 3744 float4)
#define UNROLL    8            // independent float4 loads in flight
#define THRESH    0.05f
#define NEG_INF   __int_as_float(0xFF800000)

__device__ __forceinline__ int bin_of(float s) {
  // valid only for s > 0 (positive floats: bit order == value order)
  int b = (int)(__float_as_uint(s) >> 16) - BIN_BASE;
  return b > (NB - 1) ? (NB - 1) : b;
}

// ctrl layout (ints): [0]=cand_cnt

template <int KC>
__global__ __launch_bounds__(256) void k_main(
    const float* __restrict__ hoi, const float* __restrict__ ps,
    const float* __restrict__ os, int R, int Kc,
    int* __restrict__ ctrl, int* __restrict__ rep,
    float* __restrict__ cand_v, int* __restrict__ cand_i, int cap) {
  __shared__ float lbsf[RPB + 1];
  __shared__ float2 lbs2[RPB];   // (bs[r], bs[r+1]) -> one ds_read_b64
  __shared__ int lh[WN];

  const int k = KC ? KC : Kc;
  const int r0 = blockIdx.x * RPB;
  const int nr = (R - r0) < RPB ? (R - r0) : RPB;

  if (threadIdx.x < WN) lh[threadIdx.x] = 0;
  for (int r = threadIdx.x; r < nr; r += blockDim.x)
    lbsf[r] = ps[r0 + r] * os[r0 + r];     // box_scores = p*o (matches ref)
  if (threadIdx.x == 0) lbsf[nr] = 0.0f;   // guard for the pair build
  __syncthreads();
  for (int r = threadIdx.x; r < nr; r += blockDim.x)
    lbs2[r] = make_float2(lbsf[r], lbsf[r + 1]);
  __syncthreads();

  const int base = r0 * k;                 // chunk start float index (16B-align)
  const int nfloat = nr * k;
  const int nf4 = nfloat >> 2;
  const float4* c4 = (const float4*)(hoi + base);

  auto process = [&](int t, const float4& h) {
    int i0 = 4 * t;
    int q = i0 / k;                        // constant k -> magic mul
    int rem = i0 - q * k;
    float2 b2 = lbs2[q];                   // ds_read_b64: bs[q], bs[q+1]
    float vals[4] = {h.x, h.y, h.z, h.w};
#pragma unroll
    for (int j = 0; j < 4; ++j) {
      float s = vals[j] * ((rem + j >= k) ? b2.y : b2.x);  // = hoi*bs (exact)
      if (s > VLO) {
        int b = bin_of(s);
        atomicAdd(&lh[b - WLO], 1);
        if (b >= G_REL) {
          int slot = atomicAdd(&ctrl[0], 1);
          if (slot < cap) { cand_v[slot] = s; cand_i[slot] = base + i0 + j; }
        }
      }
    }
  };

  const int BD = blockDim.x;
  for (int t0 = threadIdx.x; t0 < nf4; t0 += UNROLL * BD) {
    float4 h[UNROLL];
#pragma unroll
    for (int j = 0; j < UNROLL; ++j) {     // UNROLL independent loads in flight
      int t = t0 + j * BD;
      h[j] = c4[t < nf4 ? t : t0];
    }
#pragma unroll
    for (int j = 0; j < UNROLL; ++j) {
      int t = t0 + j * BD;
      if (t < nf4) process(t, h[j]);
    }
  }
  // scalar tail (nfloat % 4; empty when nr==RPB since 128*117 % 4 == 0)
  for (int i = (nf4 << 2) + threadIdx.x; i < nfloat; i += BD) {
    int q = i / k;
    float s = hoi[base + i] * lbsf[q];
    if (s > VLO) {
      int b = bin_of(s);
      atomicAdd(&lh[b - WLO], 1);
      if (b >= G_REL) {
        int slot = atomicAdd(&ctrl[0], 1);
        if (slot < cap) { cand_v[slot] = s; cand_i[slot] = base + i; }
      }
    }
  }

  __syncthreads();
  if (threadIdx.x < WN) {                  // 32-way replicated flush
    int c = lh[threadIdx.x];
    if (c) atomicAdd(&rep[(blockIdx.x & (NREP - 1)) * REPS + threadIdx.x], c);
  }
}

__global__ __launch_bounds__(1024) void k_post(
    const float* __restrict__ hoi, const float* __restrict__ ps,
    const float* __restrict__ os, const float4* __restrict__ pbox,
    const float4* __restrict__ obox, const int* __restrict__ ocls,
    int N, int Kc, const int* __restrict__ ctrl, const int* __restrict__ rep,
    const float* __restrict__ cand_v, const int* __restrict__ cand_i,
    int cap, float* __restrict__ out, int topk) {
  __shared__ int wh[NB];       // [0,WN) fast path; full NB on slow path
  __shared__ float sv[FCAP];
  __shared__ int si[FCAP];
  __shared__ int s_T, s_n, s_cnt, s_mode;

  if (threadIdx.x < WN) {      // reduce the 32 replicas
    int sum = 0;
#pragma unroll
    for (int r = 0; r < NREP; ++r) sum += rep[r * REPS + threadIdx.x];
    wh[threadIdx.x] = sum;
  }
  __syncthreads();
  if (threadIdx.x == 0) {
    int cum = 0, T = -1;
    for (int b = WN - 1; b >= 0; --b) {
      cum += wh[b];
      if (T < 0 && cum >= topk) T = b + WLO;
    }
    int cnt = ctrl[0];
    s_mode = (T >= G_REL && cnt <= cap) ? 1 : 0;   // 1 = fast
    s_T = T;
    s_n = cnt > cap ? cap : cnt;
    s_cnt = 0;
  }
  __syncthreads();

  if (s_mode) {
    const int T = s_T, n = s_n;
    for (int t = threadIdx.x; t < n; t += blockDim.x) {
      float v = cand_v[t];
      if (bin_of(v) >= T) {
        int slot = atomicAdd(&s_cnt, 1);
        if (slot < FCAP) { sv[slot] = v; si[slot] = cand_i[t]; }
      }
    }
  } else {
    // slow-but-exact: full histogram + re-collect (correctness net)
    for (int b = threadIdx.x; b < NB; b += blockDim.x) wh[b] = 0;
    __syncthreads();
    for (int i = threadIdx.x; i < N; i += blockDim.x) {
      int q = i / Kc;
      float s = hoi[i] * (ps[q] * os[q]);
      if (s > THRESH) atomicAdd(&wh[bin_of(s)], 1);
    }
    __syncthreads();
    if (threadIdx.x == 0) {
      int cum = 0, T = 0;
      for (int b = NB - 1; b >= 0; --b) {
        cum += wh[b];
        if (cum >= topk) { T = b; break; }
      }
      s_T = T;
    }
    __syncthreads();
    const int T = s_T;
    for (int i = threadIdx.x; i < N; i += blockDim.x) {
      int q = i / Kc;
      float s = hoi[i] * (ps[q] * os[q]);
      if (s > THRESH && bin_of(s) >= T) {
        int slot = atomicAdd(&s_cnt, 1);
        if (slot < FCAP) { sv[slot] = s; si[slot] = i; }
      }
    }
  }
  __syncthreads();

  int m = s_cnt > FCAP ? FCAP : s_cnt;
  int P = 128;                 // >= topk; dynamic power-of-2 sort size
  while (P < m) P <<= 1;
  for (int t = m + threadIdx.x; t < P; t += blockDim.x) {
    sv[t] = NEG_INF;
    si[t] = 0x7FFFFFFF;
  }
  // bitonic sort [0,P): value desc, index asc (stable-top_k tie order)
  for (int kk = 2; kk <= P; kk <<= 1) {
    for (int j = kk >> 1; j > 0; j >>= 1) {
      __syncthreads();
      for (int i = threadIdx.x; i < P; i += blockDim.x) {
        int l = i ^ j;
        if (l > i) {
          float vi = sv[i], vl = sv[l];
          int ii = si[i], il = si[l];
          bool before = (vi > vl) || (vi == vl && ii < il);
          if (((i & kk) == 0) != before) {
            sv[i] = vl; sv[l] = vi; si[i] = il; si[l] = ii;
          }
        }
      }
    }
  }
  __syncthreads();

  if ((int)threadIdx.x < topk) {
    int o = threadIdx.x;
    float v = sv[o];
    int idx = si[o];
    bool valid = (idx != 0x7FFFFFFF) && (v > THRESH);
    int safe = valid ? idx : 0;
    int pair = safe / Kc;
    int act = safe - pair * Kc;
    float4 pb = pbox[pair];
    float4 ob = obox[pair];
    // output: scores[100] | pboxes[400] | oboxes[400] | ocls[100] |
    //         action[100] | valid[100]   (all fp32)
    out[o] = valid ? v : 0.0f;
    float* pdst = out + topk + 4 * o;
    pdst[0] = pb.x; pdst[1] = pb.y; pdst[2] = pb.z; pdst[3] = pb.w;
    float* odst = out + 5 * topk + 4 * o;
    odst[0] = ob.x; odst[1] = ob.y; odst[2] = ob.z; odst[3] = ob.w;
    out[9 * topk + o] = (float)ocls[pair];
    out[10 * topk + o] = (float)act;
    out[11 * topk + o] = valid ? 1.0f : 0.0f;
  }
}

extern "C" void kernel_launch(void* const* d_in, const int* in_sizes, int n_in,
                              void* d_out, int out_size, void* d_ws, size_t ws_size,
                              hipStream_t stream) {
  const float* pbox = (const float*)d_in[0];
  const float* obox = (const float*)d_in[1];
  const float* ps   = (const float*)d_in[2];
  const float* os   = (const float*)d_in[3];
  const int*   ocls = (const int*)d_in[4];
  const float* hoi  = (const float*)d_in[5];
  float* out = (float*)d_out;

  const int R    = in_sizes[2];
  const int N    = in_sizes[5];
  const int Kc   = N / R;              // 117
  const int topk = out_size / 12;      // 100

  // ws: ctrl[64 ints] @0 | replicas 32x96 ints @256 | cand_v/cand_i @12544
  int* ctrl = (int*)d_ws;
  int* rep  = (int*)((char*)d_ws + 256);
  float* cand_v = (float*)((char*)d_ws + 12544);
  size_t cand_budget = (ws_size > 12544) ? (ws_size - 12544) / 8 : 1024;
  int cap = cand_budget > 8192 ? 8192 : (int)cand_budget;
  int* cand_i = (int*)((char*)d_ws + 12544 + (size_t)cap * sizeof(float));

  hipMemsetAsync(d_ws, 0, 12544, stream);   // zero ctrl + replicas

  const int nblocks = (R + RPB - 1) / RPB;  // 2048 for R=262144
  if (Kc == 117) {
    k_main<117><<<nblocks, 256, 0, stream>>>(hoi, ps, os, R, Kc, ctrl, rep,
                                             cand_v, cand_i, cap);
  } else {
    k_main<0><<<nblocks, 256, 0, stream>>>(hoi, ps, os, R, Kc, ctrl, rep,
                                           cand_v, cand_i, cap);
  }
  k_post<<<1, 1024, 0, stream>>>(hoi, ps, os, (const float4*)pbox,
                                 (const float4*)obox, ocls, N, Kc, ctrl, rep,
                                 cand_v, cand_i, cap, out, topk);
}

// Round 7
// 209.293 us; speedup vs baseline: 2.4685x; 1.0285x over previous
//
#include <hip/hip_runtime.h>

// ---------------------------------------------------------------------------
// HOI top-k, R=262144 x K=117, topk=100, thresh=0.05
//
//  K1 k_main : minimal streaming pass. Block b owns RPB=128 rows (= exactly
//              3744 float4s, 16B-aligned). bs[r]=ps*os staged once into LDS
//              as duplicated float2 pairs. Hot loop: 1 global float4 +
//              1 ds_read_b64 + 4 mul + 4 cmp; values s > CSEL=0.95 appended
//              to a global buffer (expected ~690 for this data). NO histogram,
//              NO fences.
//  K2 k_post : 1 block. If topk <= cnt <= FCAP: the exact top-k is a subset
//              of the buffer -> bitonic sort (value desc, index asc = stable
//              top_k tie order), write outputs. Otherwise: exact single-block
//              recompute (576-bin histogram + collect) — distribution-
//              independent correctness net, never taken on this data.
// ---------------------------------------------------------------------------

#define NB        576          // slow-path histogram bins
#define BIN_BASE  15692        // (bits of 0.05f) >> 16
#define CSEL      0.95f        // fast-path collect threshold
#define FCAP      2048         // sort capacity (power of 2), 16 KiB LDS
#define RPB       128          // rows per block (128*117 floats = 3744 float4)
#define UNROLL    8            // independent float4 loads in flight
#define THRESH    0.05f
#define NEG_INF   __int_as_float(0xFF800000)

__device__ __forceinline__ int bin_of(float s) {
  // valid only for s > 0 (positive floats: bit order == value order)
  int b = (int)(__float_as_uint(s) >> 16) - BIN_BASE;
  return b > (NB - 1) ? (NB - 1) : b;
}

// ctrl layout (ints): [0]=cand_cnt

template <int KC>
__global__ __launch_bounds__(256) void k_main(
    const float* __restrict__ hoi, const float* __restrict__ ps,
    const float* __restrict__ os, int R, int Kc,
    int* __restrict__ ctrl, float* __restrict__ cand_v,
    int* __restrict__ cand_i, int cap) {
  __shared__ float lbsf[RPB + 1];
  __shared__ float2 lbs2[RPB];   // (bs[r], bs[r+1]) -> one ds_read_b64

  const int k = KC ? KC : Kc;
  const int r0 = blockIdx.x * RPB;
  const int nr = (R - r0) < RPB ? (R - r0) : RPB;

  for (int r = threadIdx.x; r < nr; r += blockDim.x)
    lbsf[r] = ps[r0 + r] * os[r0 + r];     // box_scores = p*o (matches ref)
  if (threadIdx.x == 0) lbsf[nr] = 0.0f;   // guard for the pair build
  __syncthreads();
  for (int r = threadIdx.x; r < nr; r += blockDim.x)
    lbs2[r] = make_float2(lbsf[r], lbsf[r + 1]);
  __syncthreads();

  const int base = r0 * k;                 // chunk start float index (16B-align)
  const int nfloat = nr * k;
  const int nf4 = nfloat >> 2;
  const float4* c4 = (const float4*)(hoi + base);

  auto process = [&](int t, const float4& h) {
    int i0 = 4 * t;
    int q = i0 / k;                        // constant k -> magic mul
    int rem = i0 - q * k;
    float2 b2 = lbs2[q];                   // ds_read_b64: bs[q], bs[q+1]
    float vals[4] = {h.x, h.y, h.z, h.w};
#pragma unroll
    for (int j = 0; j < 4; ++j) {
      float s = vals[j] * ((rem + j >= k) ? b2.y : b2.x);  // = hoi*bs (exact)
      if (s > CSEL) {                      // rare (~2e-5)
        int slot = atomicAdd(&ctrl[0], 1);
        if (slot < cap) { cand_v[slot] = s; cand_i[slot] = base + i0 + j; }
      }
    }
  };

  const int BD = blockDim.x;
  for (int t0 = threadIdx.x; t0 < nf4; t0 += UNROLL * BD) {
    float4 h[UNROLL];
#pragma unroll
    for (int j = 0; j < UNROLL; ++j) {     // UNROLL independent loads in flight
      int t = t0 + j * BD;
      h[j] = c4[t < nf4 ? t : t0];
    }
#pragma unroll
    for (int j = 0; j < UNROLL; ++j) {
      int t = t0 + j * BD;
      if (t < nf4) process(t, h[j]);
    }
  }
  // scalar tail (nfloat % 4; empty when nr==RPB since 128*117 % 4 == 0)
  for (int i = (nf4 << 2) + threadIdx.x; i < nfloat; i += BD) {
    int q = i / k;
    float s = hoi[base + i] * lbsf[q];
    if (s > CSEL) {
      int slot = atomicAdd(&ctrl[0], 1);
      if (slot < cap) { cand_v[slot] = s; cand_i[slot] = base + i; }
    }
  }
}

__global__ __launch_bounds__(1024) void k_post(
    const float* __restrict__ hoi, const float* __restrict__ ps,
    const float* __restrict__ os, const float4* __restrict__ pbox,
    const float4* __restrict__ obox, const int* __restrict__ ocls,
    int N, int Kc, const int* __restrict__ ctrl,
    const float* __restrict__ cand_v, const int* __restrict__ cand_i,
    int cap, float* __restrict__ out, int topk) {
  __shared__ float sv[FCAP];
  __shared__ int si[FCAP];
  __shared__ int wh[NB];                   // slow path only
  __shared__ int s_T, s_cnt;

  int cnt = ctrl[0];
  bool fast = (cnt >= topk && cnt <= FCAP);

  if (fast) {
    for (int t = threadIdx.x; t < cnt; t += blockDim.x) {
      sv[t] = cand_v[t];
      si[t] = cand_i[t];
    }
    if (threadIdx.x == 0) s_cnt = cnt;
  } else {
    // slow-but-exact: full histogram + re-collect (correctness net)
    for (int b = threadIdx.x; b < NB; b += blockDim.x) wh[b] = 0;
    if (threadIdx.x == 0) s_cnt = 0;
    __syncthreads();
    for (int i = threadIdx.x; i < N; i += blockDim.x) {
      int q = i / Kc;
      float s = hoi[i] * (ps[q] * os[q]);
      if (s > THRESH) atomicAdd(&wh[bin_of(s)], 1);
    }
    __syncthreads();
    if (threadIdx.x == 0) {
      int cum = 0, T = 0;
      for (int b = NB - 1; b >= 0; --b) {
        cum += wh[b];
        if (cum >= topk) { T = b; break; }
      }
      s_T = T;
    }
    __syncthreads();
    const int T = s_T;
    for (int i = threadIdx.x; i < N; i += blockDim.x) {
      int q = i / Kc;
      float s = hoi[i] * (ps[q] * os[q]);
      if (s > THRESH && bin_of(s) >= T) {
        int slot = atomicAdd(&s_cnt, 1);
        if (slot < FCAP) { sv[slot] = s; si[slot] = i; }
      }
    }
  }
  __syncthreads();

  int m = s_cnt > FCAP ? FCAP : s_cnt;
  int P = 128;                 // >= topk; dynamic power-of-2 sort size
  while (P < m) P <<= 1;
  for (int t = m + threadIdx.x; t < P; t += blockDim.x) {
    sv[t] = NEG_INF;
    si[t] = 0x7FFFFFFF;
  }
  // bitonic sort [0,P): value desc, index asc (stable-top_k tie order)
  for (int kk = 2; kk <= P; kk <<= 1) {
    for (int j = kk >> 1; j > 0; j >>= 1) {
      __syncthreads();
      for (int i = threadIdx.x; i < P; i += blockDim.x) {
        int l = i ^ j;
        if (l > i) {
          float vi = sv[i], vl = sv[l];
          int ii = si[i], il = si[l];
          bool before = (vi > vl) || (vi == vl && ii < il);
          if (((i & kk) == 0) != before) {
            sv[i] = vl; sv[l] = vi; si[i] = il; si[l] = ii;
          }
        }
      }
    }
  }
  __syncthreads();

  if ((int)threadIdx.x < topk) {
    int o = threadIdx.x;
    float v = sv[o];
    int idx = si[o];
    bool valid = (idx != 0x7FFFFFFF) && (v > THRESH);
    int safe = valid ? idx : 0;
    int pair = safe / Kc;
    int act = safe - pair * Kc;
    float4 pb = pbox[pair];
    float4 ob = obox[pair];
    // output: scores[100] | pboxes[400] | oboxes[400] | ocls[100] |
    //         action[100] | valid[100]   (all fp32)
    out[o] = valid ? v : 0.0f;
    float* pdst = out + topk + 4 * o;
    pdst[0] = pb.x; pdst[1] = pb.y; pdst[2] = pb.z; pdst[3] = pb.w;
    float* odst = out + 5 * topk + 4 * o;
    odst[0] = ob.x; odst[1] = ob.y; odst[2] = ob.z; odst[3] = ob.w;
    out[9 * topk + o] = (float)ocls[pair];
    out[10 * topk + o] = (float)act;
    out[11 * topk + o] = valid ? 1.0f : 0.0f;
  }
}

extern "C" void kernel_launch(void* const* d_in, const int* in_sizes, int n_in,
                              void* d_out, int out_size, void* d_ws, size_t ws_size,
                              hipStream_t stream) {
  const float* pbox = (const float*)d_in[0];
  const float* obox = (const float*)d_in[1];
  const float* ps   = (const float*)d_in[2];
  const float* os   = (const float*)d_in[3];
  const int*   ocls = (const int*)d_in[4];
  const float* hoi  = (const float*)d_in[5];
  float* out = (float*)d_out;

  const int R    = in_sizes[2];
  const int N    = in_sizes[5];
  const int Kc   = N / R;              // 117
  const int topk = out_size / 12;      // 100

  // ws: ctrl[64 ints] @0 | cand_v @4096 | cand_i after
  int* ctrl = (int*)d_ws;
  float* cand_v = (float*)((char*)d_ws + 4096);
  size_t cand_budget = (ws_size > 4096) ? (ws_size - 4096) / 8 : 1024;
  int cap = cand_budget > 4096 ? 4096 : (int)cand_budget;
  int* cand_i = (int*)((char*)d_ws + 4096 + (size_t)cap * sizeof(float));

  hipMemsetAsync(d_ws, 0, 256, stream);     // zero ctrl

  const int nblocks = (R + RPB - 1) / RPB;  // 2048 for R=262144
  if (Kc == 117) {
    k_main<117><<<nblocks, 256, 0, stream>>>(hoi, ps, os, R, Kc, ctrl,
                                             cand_v, cand_i, cap);
  } else {
    k_main<0><<<nblocks, 256, 0, stream>>>(hoi, ps, os, R, Kc, ctrl,
                                           cand_v, cand_i, cap);
  }
  k_post<<<1, 1024, 0, stream>>>(hoi, ps, os, (const float4*)pbox,
                                 (const float4*)obox, ocls, N, Kc, ctrl,
                                 cand_v, cand_i, cap, out, topk);
}

// Round 9
// 207.827 us; speedup vs baseline: 2.4859x; 1.0071x over previous
//
#include <hip/hip_runtime.h>

// ---------------------------------------------------------------------------
// HOI top-k, R=262144 x K=117, topk=100, thresh=0.05
//
//  K1 k_main : minimal streaming pass. Block b owns RPB=512 rows (= exactly
//              14976 float4s, 16B-aligned chunk). bs[r]=ps*os staged once
//              into LDS as duplicated float2 pairs. Per trip, three phases:
//              8 nontemporal 16B loads -> 8 ds_read_b64 -> 8x4 mul+cmp;
//              values s > CSEL=0.95 appended to a global buffer (~690 for
//              this data). NO histogram, NO fences.
//  K2 k_post : 1 block. If topk <= cnt <= FCAP: exact top-k is a subset of
//              the buffer -> bitonic sort (value desc, index asc = stable
//              top_k tie order), write outputs. Otherwise: exact single-block
//              recompute (576-bin histogram + collect) — distribution-
//              independent correctness net, never taken on this data.
// ---------------------------------------------------------------------------

#define NB        576          // slow-path histogram bins
#define BIN_BASE  15692        // (bits of 0.05f) >> 16
#define CSEL      0.95f        // fast-path collect threshold
#define FCAP      2048         // sort capacity (power of 2), 16 KiB LDS
#define RPB       512          // rows per block (512*117 floats = 14976 f4)
#define UNROLL    8            // independent float4 loads in flight
#define THRESH    0.05f
#define NEG_INF   __int_as_float(0xFF800000)

typedef float floatx4 __attribute__((ext_vector_type(4)));  // nt-load-able

__device__ __forceinline__ int bin_of(float s) {
  // valid only for s > 0 (positive floats: bit order == value order)
  int b = (int)(__float_as_uint(s) >> 16) - BIN_BASE;
  return b > (NB - 1) ? (NB - 1) : b;
}

// ctrl layout (ints): [0]=cand_cnt

template <int KC>
__global__ __launch_bounds__(256) void k_main(
    const float* __restrict__ hoi, const float* __restrict__ ps,
    const float* __restrict__ os, int R, int Kc,
    int* __restrict__ ctrl, float* __restrict__ cand_v,
    int* __restrict__ cand_i, int cap) {
  __shared__ float lbsf[RPB + 1];
  __shared__ float2 lbs2[RPB];   // (bs[r], bs[r+1]) -> one ds_read_b64

  const int k = KC ? KC : Kc;
  const int r0 = blockIdx.x * RPB;
  const int nr = (R - r0) < RPB ? (R - r0) : RPB;

  for (int r = threadIdx.x; r < nr; r += blockDim.x)
    lbsf[r] = ps[r0 + r] * os[r0 + r];     // box_scores = p*o (matches ref)
  if (threadIdx.x == 0) lbsf[nr] = 0.0f;   // guard for the pair build
  __syncthreads();
  for (int r = threadIdx.x; r < nr; r += blockDim.x)
    lbs2[r] = make_float2(lbsf[r], lbsf[r + 1]);
  __syncthreads();

  const int base = r0 * k;                 // chunk start float index (16B-align)
  const int nfloat = nr * k;
  const int nf4 = nfloat >> 2;
  const floatx4* c4 = (const floatx4*)(hoi + base);

  const int BD = blockDim.x;
  for (int t0 = threadIdx.x; t0 < nf4; t0 += UNROLL * BD) {
    int tt[UNROLL];
    floatx4 h[UNROLL];
#pragma unroll
    for (int j = 0; j < UNROLL; ++j) {     // phase 1: UNROLL nt loads in flight
      int t = t0 + j * BD;
      tt[j] = t < nf4 ? t : t0;            // clamp (dup load -> L1 hit)
      h[j] = __builtin_nontemporal_load(c4 + tt[j]);
    }
    int i0[UNROLL], rem[UNROLL];
    float2 b2[UNROLL];
#pragma unroll
    for (int j = 0; j < UNROLL; ++j) {     // phase 2: UNROLL ds_read_b64
      i0[j] = 4 * tt[j];
      int q = i0[j] / k;                   // constant k -> magic mul
      rem[j] = i0[j] - q * k;
      b2[j] = lbs2[q];
    }
#pragma unroll
    for (int j = 0; j < UNROLL; ++j) {     // phase 3: compute + rare append
      if (t0 + j * BD < nf4) {
        float vals[4] = {h[j].x, h[j].y, h[j].z, h[j].w};
#pragma unroll
        for (int e = 0; e < 4; ++e) {
          float s = vals[e] * ((rem[j] + e >= k) ? b2[j].y : b2[j].x);
          if (s > CSEL) {                  // rare (~2e-5)
            int slot = atomicAdd(&ctrl[0], 1);
            if (slot < cap) { cand_v[slot] = s; cand_i[slot] = i0[j] + base + e; }
          }
        }
      }
    }
  }
  // scalar tail (nfloat % 4; empty when nr==RPB since 512*117 % 4 == 0)
  for (int i = (nf4 << 2) + threadIdx.x; i < nfloat; i += BD) {
    int q = i / k;
    float s = hoi[base + i] * lbsf[q];
    if (s > CSEL) {
      int slot = atomicAdd(&ctrl[0], 1);
      if (slot < cap) { cand_v[slot] = s; cand_i[slot] = base + i; }
    }
  }
}

__global__ __launch_bounds__(1024) void k_post(
    const float* __restrict__ hoi, const float* __restrict__ ps,
    const float* __restrict__ os, const float4* __restrict__ pbox,
    const float4* __restrict__ obox, const int* __restrict__ ocls,
    int N, int Kc, const int* __restrict__ ctrl,
    const float* __restrict__ cand_v, const int* __restrict__ cand_i,
    int cap, float* __restrict__ out, int topk) {
  __shared__ float sv[FCAP];
  __shared__ int si[FCAP];
  __shared__ int wh[NB];                   // slow path only
  __shared__ int s_T, s_cnt;

  int cnt = ctrl[0];
  bool fast = (cnt >= topk && cnt <= FCAP);

  if (fast) {
    for (int t = threadIdx.x; t < cnt; t += blockDim.x) {
      sv[t] = cand_v[t];
      si[t] = cand_i[t];
    }
    if (threadIdx.x == 0) s_cnt = cnt;
  } else {
    // slow-but-exact: full histogram + re-collect (correctness net)
    for (int b = threadIdx.x; b < NB; b += blockDim.x) wh[b] = 0;
    if (threadIdx.x == 0) s_cnt = 0;
    __syncthreads();
    for (int i = threadIdx.x; i < N; i += blockDim.x) {
      int q = i / Kc;
      float s = hoi[i] * (ps[q] * os[q]);
      if (s > THRESH) atomicAdd(&wh[bin_of(s)], 1);
    }
    __syncthreads();
    if (threadIdx.x == 0) {
      int cum = 0, T = 0;
      for (int b = NB - 1; b >= 0; --b) {
        cum += wh[b];
        if (cum >= topk) { T = b; break; }
      }
      s_T = T;
    }
    __syncthreads();
    const int T = s_T;
    for (int i = threadIdx.x; i < N; i += blockDim.x) {
      int q = i / Kc;
      float s = hoi[i] * (ps[q] * os[q]);
      if (s > THRESH && bin_of(s) >= T) {
        int slot = atomicAdd(&s_cnt, 1);
        if (slot < FCAP) { sv[slot] = s; si[slot] = i; }
      }
    }
  }
  __syncthreads();

  int m = s_cnt > FCAP ? FCAP : s_cnt;
  int P = 128;                 // >= topk; dynamic power-of-2 sort size
  while (P < m) P <<= 1;
  for (int t = m + threadIdx.x; t < P; t += blockDim.x) {
    sv[t] = NEG_INF;
    si[t] = 0x7FFFFFFF;
  }
  // bitonic sort [0,P): value desc, index asc (stable-top_k tie order)
  for (int kk = 2; kk <= P; kk <<= 1) {
    for (int j = kk >> 1; j > 0; j >>= 1) {
      __syncthreads();
      for (int i = threadIdx.x; i < P; i += blockDim.x) {
        int l = i ^ j;
        if (l > i) {
          float vi = sv[i], vl = sv[l];
          int ii = si[i], il = si[l];
          bool before = (vi > vl) || (vi == vl && ii < il);
          if (((i & kk) == 0) != before) {
            sv[i] = vl; sv[l] = vi; si[i] = il; si[l] = ii;
          }
        }
      }
    }
  }
  __syncthreads();

  if ((int)threadIdx.x < topk) {
    int o = threadIdx.x;
    float v = sv[o];
    int idx = si[o];
    bool valid = (idx != 0x7FFFFFFF) && (v > THRESH);
    int safe = valid ? idx : 0;
    int pair = safe / Kc;
    int act = safe - pair * Kc;
    float4 pb = pbox[pair];
    float4 ob = obox[pair];
    // output: scores[100] | pboxes[400] | oboxes[400] | ocls[100] |
    //         action[100] | valid[100]   (all fp32)
    out[o] = valid ? v : 0.0f;
    float* pdst = out + topk + 4 * o;
    pdst[0] = pb.x; pdst[1] = pb.y; pdst[2] = pb.z; pdst[3] = pb.w;
    float* odst = out + 5 * topk + 4 * o;
    odst[0] = ob.x; odst[1] = ob.y; odst[2] = ob.z; odst[3] = ob.w;
    out[9 * topk + o] = (float)ocls[pair];
    out[10 * topk + o] = (float)act;
    out[11 * topk + o] = valid ? 1.0f : 0.0f;
  }
}

extern "C" void kernel_launch(void* const* d_in, const int* in_sizes, int n_in,
                              void* d_out, int out_size, void* d_ws, size_t ws_size,
                              hipStream_t stream) {
  const float* pbox = (const float*)d_in[0];
  const float* obox = (const float*)d_in[1];
  const float* ps   = (const float*)d_in[2];
  const float* os   = (const float*)d_in[3];
  const int*   ocls = (const int*)d_in[4];
  const float* hoi  = (const float*)d_in[5];
  float* out = (float*)d_out;

  const int R    = in_sizes[2];
  const int N    = in_sizes[5];
  const int Kc   = N / R;              // 117
  const int topk = out_size / 12;      // 100

  // ws: ctrl[64 ints] @0 | cand_v @4096 | cand_i after
  int* ctrl = (int*)d_ws;
  float* cand_v = (float*)((char*)d_ws + 4096);
  size_t cand_budget = (ws_size > 4096) ? (ws_size - 4096) / 8 : 1024;
  int cap = cand_budget > 4096 ? 4096 : (int)cand_budget;
  int* cand_i = (int*)((char*)d_ws + 4096 + (size_t)cap * sizeof(float));

  (void)hipMemsetAsync(d_ws, 0, 256, stream);   // zero ctrl

  const int nblocks = (R + RPB - 1) / RPB;      // 512 for R=262144
  if (Kc == 117) {
    k_main<117><<<nblocks, 256, 0, stream>>>(hoi, ps, os, R, Kc, ctrl,
                                             cand_v, cand_i, cap);
  } else {
    k_main<0><<<nblocks, 256, 0, stream>>>(hoi, ps, os, R, Kc, ctrl,
                                           cand_v, cand_i, cap);
  }
  k_post<<<1, 1024, 0, stream>>>(hoi, ps, os, (const float4*)pbox,
                                 (const float4*)obox, ocls, N, Kc, ctrl,
                                 cand_v, cand_i, cap, out, topk);
}